// Round 7
// baseline (4683.867 us; speedup 1.0000x reference)
//
#include <hip/hip_runtime.h>

typedef __attribute__((ext_vector_type(8))) short short8;
typedef __attribute__((ext_vector_type(4))) float f32x4;

#define MFMA(a,b,c) __builtin_amdgcn_mfma_f32_16x16x32_bf16(a,b,c,0,0,0)

// Problem dims
#define S_LEN 128
#define IN_D  8
#define HID   512
#define NL    3
#define HSTR  536       // bf16 h row stride (shorts)

// ws layout (bytes)
#define OFF_WHH  0                       // [3][32][16][3][64][8] bf16 = 4,718,592
#define OFF_WIH  (4718592)               // [3][32][3][64][8] bf16    =   294,912
#define OFF_FLAG (4718592 + 294912)      // 256 * int                 =     1,024
#define OFF_XCHG (OFF_FLAG + 1024)       // 256 blk * 2 slot * 16 KB  = 8,388,608

__device__ __forceinline__ unsigned short f2bf(float f){
  unsigned u = __float_as_uint(f);
  u += 0x7FFFu + ((u >> 16) & 1u);     // round-to-nearest-even
  return (unsigned short)(u >> 16);
}

// async global->LDS, 16B per lane: dst = uniform base + lane*16 (HW); src is per-lane
__device__ __forceinline__ void gll16(const unsigned short* g, unsigned short* l){
  __builtin_amdgcn_global_load_lds(
      (const __attribute__((address_space(1))) unsigned int*)g,
      (__attribute__((address_space(3))) unsigned int*)l,
      16, 0, 0);
}

// Pack Whh [3][1536][512] f32 -> bf16 B-fragments, gate-interleaved per kk:
// dst chunk gid = (((l*32+nt)*16+kk)*3+g)*64+lane ; holds Whh[l][g*512+nt*16+(lane&15)][kk*32+(lane>>4)*8+j]
__global__ void prep_whh(const float* __restrict__ Whh, unsigned short* __restrict__ Wp){
  int gid = blockIdx.x * 256 + threadIdx.x;     // 294912 total
  int lane = gid & 63;
  int r = gid >> 6;
  int g  = r % 3;  r /= 3;
  int kk = r & 15; r >>= 4;
  int nt = r & 31;
  int l  = r >> 5;
  int n  = g * 512 + nt * 16 + (lane & 15);
  int k0 = kk * 32 + (lane >> 4) * 8;
  const float* src = Whh + ((size_t)l * 1536 + n) * 512 + k0;
  unsigned short t[8];
#pragma unroll
  for (int j = 0; j < 8; ++j) t[j] = f2bf(src[j]);
  uint4 v;
  v.x = t[0] | ((unsigned)t[1] << 16);
  v.y = t[2] | ((unsigned)t[3] << 16);
  v.z = t[4] | ((unsigned)t[5] << 16);
  v.w = t[6] | ((unsigned)t[7] << 16);
  *(uint4*)(Wp + (size_t)gid * 8) = v;
}

// Pack Wih [3][1536][8] -> zero-padded (K=8 of 32) B-fragments, gate-interleaved:
// dst chunk gid = ((l*32+nt)*3+g)*64+lane
__global__ void prep_wih(const float* __restrict__ Wih, unsigned short* __restrict__ Wip){
  int gid = blockIdx.x * 256 + threadIdx.x;     // 18432 total
  int lane = gid & 63;
  int r = gid >> 6;
  int g  = r % 3;  r /= 3;
  int nt = r & 31;
  int l  = r >> 5;
  unsigned short t[8] = {0,0,0,0,0,0,0,0};
  if ((lane >> 4) == 0){
    int n = g * 512 + nt * 16 + (lane & 15);
    const float* src = Wih + ((size_t)l * 1536 + n) * 8;
#pragma unroll
    for (int j = 0; j < 8; ++j) t[j] = f2bf(src[j]);
  }
  uint4 v;
  v.x = t[0] | ((unsigned)t[1] << 16);
  v.y = t[2] | ((unsigned)t[3] << 16);
  v.z = t[4] | ((unsigned)t[5] << 16);
  v.w = t[6] | ((unsigned)t[7] << 16);
  *(uint4*)(Wip + (size_t)gid * 8) = v;
}

// Main: 256 blocks x 1024 threads (16 waves), 1 block/CU.
// Pair (bid, bid^4) shares batch rows [b0,b0+32); each computes 256 of 512 cols.
// Weight latency hidden via depth-2 pipeline: R,Z frags staged LDS by global_load_lds,
// N frag in a 2-slot register pipeline; s_waitcnt vmcnt(3) counted (never 0 mid-loop).
__global__ __launch_bounds__(1024) void gru_main(
    const float* __restrict__ x,
    const unsigned short* __restrict__ Wp,
    const unsigned short* __restrict__ Wip,
    const float* __restrict__ bih,
    const float* __restrict__ bhh,
    float* __restrict__ out,
    int* __restrict__ flags,
    unsigned int* __restrict__ xchg)
{
  __shared__ __align__(16) unsigned short hB[2][32 * HSTR];       // 68,608 B
  __shared__ __align__(16) unsigned short stageRZ[16][2][2][512]; // 65,536 B: [wave][buf][R/Z][1KB frag]
  __shared__ __align__(16) unsigned short xpack[2][1024];         //  4,096 B
  __shared__ float sBrz[3 * 512];                                 //  6,144 B (own half r,z)
  __shared__ float sBni[3 * 256];                                 //  3,072 B
  __shared__ float sBnh[3 * 256];                                 //  3,072 B

  const int tid  = threadIdx.x;
  const int wv   = tid >> 6;
  const int lane = tid & 63;
  const int l15  = lane & 15;
  const int l4   = lane >> 4;

  const int bid     = blockIdx.x;
  const int bgroup  = ((bid >> 3) << 2) | (bid & 3);   // [0,128)
  const int half    = (bid >> 2) & 1;
  const int partner = bid ^ 4;
  const int b0      = bgroup * 32;
  const int cl      = wv * 16 + l15;                   // local col (0..255)
  const int col     = half * 256 + cl;                 // global col
  const int ntc     = half * 16 + wv;                  // global 16-col tile index
  const int pcb0    = (1 - half) * 256;                // partner's column base
  const int ko0     = half * 8;                        // own-half kk range start
  const int pk0     = 8 - ko0;                         // partner-half kk range start

  unsigned int* xown = xchg + (size_t)bid * 8192;      // 2 slots x 4096 u32

  for (int i = tid; i < 32 * HSTR; i += 1024){ hB[0][i] = 0; }
  for (int i = tid; i < 1536; i += 1024){
    int l = i / 512, c = i % 512;
    int gc = half * 256 + (c & 255);
    sBrz[i] = (c < 256) ? (bih[l * 1536 + gc] + bhh[l * 1536 + gc])
                        : (bih[l * 1536 + 512 + gc] + bhh[l * 1536 + 512 + gc]);
  }
  if (tid < 768){
    int l = tid / 256, c = tid % 256;
    int gc = l * 1536 + 1024 + half * 256 + c;
    sBni[tid] = bih[gc];
    sBnh[tid] = bhh[gc];
  }

  // fp32 h master in registers: [m][q] -> batch row m*16+l4*4+q, this lane's col
  float hreg[2][4];
#pragma unroll
  for (int m = 0; m < 2; ++m)
#pragma unroll
    for (int q = 0; q < 4; ++q) hreg[m][q] = 0.f;

  // xpack writer mapping: tid = (m*64+lane)*8 + j
  const int xm = tid >> 9, xl = (tid >> 3) & 63, xj = tid & 7;
  const size_t xbase = ((size_t)(b0 + xm * 16 + (xl & 15))) * (S_LEN * IN_D) + xj;
  const int xvalid = (xl < 16);
  { // stage x(t=0)
    float xv = xvalid ? x[xbase] : 0.f;
    xpack[0][tid] = f2bf(xv);
  }
  __syncthreads();

  const int aoff0 = l15 * HSTR + l4 * 8;          // A-frag m=0 (rows 0..15), shorts
  const int aoff1 = aoff0 + 16 * HSTR;            // A-frag m=1 (rows 16..31)

  const unsigned short* wklB = Wp  + (size_t)ntc * 48 * 512 + (size_t)lane * 8;
  const unsigned short* wilB = Wip + (size_t)ntc * 3  * 512 + (size_t)lane * 8;

#define PREF(kk_, buf_, nbv) { \
    const unsigned short* wsrc_ = wkl + (kk_) * 1536; \
    gll16(wsrc_,       &stageRZ[wv][buf_][0][0]); \
    gll16(wsrc_ + 512, &stageRZ[wv][buf_][1][0]); \
    nbv = *(const short8*)(wsrc_ + 1024); \
  }
#define WAIT3 asm volatile("s_waitcnt vmcnt(3)" ::: "memory")
#define WAIT0 asm volatile("s_waitcnt vmcnt(0)" ::: "memory")
#define CONSUME(kk_, buf_, nbv) { \
    short8 bR = *(const short8*)(&stageRZ[wv][buf_][0][lane * 8]); \
    short8 bZ = *(const short8*)(&stageRZ[wv][buf_][1][lane * 8]); \
    short8 a0 = *(const short8*)(hbc + aoff0 + (kk_) * 32); \
    short8 a1 = *(const short8*)(hbc + aoff1 + (kk_) * 32); \
    accR0 = MFMA(a0, bR, accR0);  accR1 = MFMA(a1, bR, accR1); \
    accZ0 = MFMA(a0, bZ, accZ0);  accZ1 = MFMA(a1, bZ, accZ1); \
    accN0 = MFMA(a0, nbv, accN0); accN1 = MFMA(a1, nbv, accN1); \
  }

  int cur = 0;
#pragma unroll 1
  for (int t = 0; t < S_LEN; ++t){
    const unsigned short* xp = &xpack[t & 1][0];
#pragma unroll 1
    for (int l = 0; l < NL; ++l){
      const int s    = t * NL + l;
      const int last = (s == S_LEN * NL - 1);
      const unsigned short* hbc = hB[cur];
      unsigned short*       hbw = hB[cur];         // partner-copy dest (same buffer)
      unsigned short*       hbn = hB[cur ^ 1];

      const unsigned short* wkl = wklB + (size_t)l * (32 * 48 * 512);
      short8 nb0, nb1;

      // ---- issue gi loads FIRST (so their auto-wait is vmcnt(3), keeping PREF in flight) ----
      const unsigned short* wil = wilB + (size_t)l * (32 * 3 * 512);
      short8 iR = *(const short8*)(wil);
      short8 iZ = *(const short8*)(wil + 512);
      short8 iN = *(const short8*)(wil + 1024);
      // ---- prime weight pipeline (does not depend on partner flag) ----
      PREF(ko0, 0, nb0);

      // ---- poll partner flag + overlap 16KB mailbox copy into hB partner half ----
      if (s > 0){
        while (__hip_atomic_load(&flags[partner], __ATOMIC_RELAXED, __HIP_MEMORY_SCOPE_AGENT) < s)
          __builtin_amdgcn_s_sleep(4);
        const unsigned int* src = xchg + ((size_t)partner * 2 + ((s - 1) & 1)) * 4096;
#pragma unroll
        for (int e = 0; e < 4; ++e){
          int f = e * 1024 + tid;                  // u32 idx: row*128 + colpair
          unsigned v = __hip_atomic_load(src + f, __ATOMIC_RELAXED, __HIP_MEMORY_SCOPE_AGENT);
          int row = f >> 7, cp = f & 127;
          *(unsigned*)(hbw + row * HSTR + pcb0 + cp * 2) = v;
        }
      }

      // ---- biases from LDS ----
      const float vR  = sBrz[l * 512 + cl];
      const float vZ  = sBrz[l * 512 + 256 + cl];
      const float vNi = sBni[l * 256 + cl];
      const float vNh = sBnh[l * 256 + cl];
      f32x4 accR0 = {vR,vR,vR,vR},     accR1 = {vR,vR,vR,vR};
      f32x4 accZ0 = {vZ,vZ,vZ,vZ},     accZ1 = {vZ,vZ,vZ,vZ};
      f32x4 accN0 = {vNh,vNh,vNh,vNh}, accN1 = {vNh,vNh,vNh,vNh};
      f32x4 giN0  = {vNi,vNi,vNi,vNi}, giN1  = {vNi,vNi,vNi,vNi};

      // ---- gi = x_t @ Wih^T (zero-padded K=8 fragments) ----
      {
        short8 ax0 = *(const short8*)(xp + lane * 8);
        short8 ax1 = *(const short8*)(xp + 512 + lane * 8);
        accR0 = MFMA(ax0, iR, accR0);  accR1 = MFMA(ax1, iR, accR1);
        accZ0 = MFMA(ax0, iZ, accZ0);  accZ1 = MFMA(ax1, iZ, accZ1);
        giN0  = MFMA(ax0, iN, giN0);   giN1  = MFMA(ax1, iN, giN1);
      }

      // ---- own-half kk (K cols this block wrote last step), depth-2 pipeline ----
#pragma unroll
      for (int kx = 0; kx < 8; ++kx){
        const int kk = ko0 + kx;
        if (kx & 1){
          if (kx < 7) PREF(kk + 1, 0, nb0) else PREF(pk0, 0, nb0);
          WAIT3;
          CONSUME(kk, 1, nb1);
        } else {
          if (kx < 7) PREF(kk + 1, 1, nb1) else PREF(pk0, 1, nb1);
          WAIT3;
          CONSUME(kk, 0, nb0);
        }
      }

      __syncthreads();   // partner-half copy visible (also drains cross-barrier PREF)

      // ---- partner-half kk ----
#pragma unroll
      for (int kx = 0; kx < 8; ++kx){
        const int kk = pk0 + kx;
        if (kx & 1){
          if (kx < 7){ PREF(kk + 1, 0, nb0); WAIT3; } else { WAIT0; }
          CONSUME(kk, 1, nb1);
        } else {
          if (kx < 7){ PREF(kk + 1, 1, nb1); WAIT3; } else { WAIT0; }
          CONSUME(kk, 0, nb0);
        }
      }

      // ---- gates; write own half to hB[cur^1] + mailbox slot s&1 ----
      unsigned int* xob = xown + (s & 1) * 4096;
#pragma unroll
      for (int m = 0; m < 2; ++m){
        f32x4 aR  = m ? accR1 : accR0;
        f32x4 aZ  = m ? accZ1 : accZ0;
        f32x4 aN4 = m ? accN1 : accN0;
        f32x4 gN  = m ? giN1  : giN0;
#pragma unroll
        for (int q = 0; q < 4; ++q){
          int b = m * 16 + l4 * 4 + q;           // batch row within tile
          float r  = 1.f / (1.f + __expf(-aR[q]));
          float z  = 1.f / (1.f + __expf(-aZ[q]));
          float aN = gN[q] + r * aN4[q];
          float n  = 1.f - 2.f / (1.f + __expf(2.f * aN));
          float hn = n + z * (hreg[m][q] - n);   // (1-z)*n + z*h
          hreg[m][q] = hn;
          unsigned bf = f2bf(hn);
          unsigned pb = (unsigned)__shfl_xor((int)bf, 1);
          if (!(l15 & 1)){
            unsigned pk = bf | (pb << 16);
            *(unsigned*)(hbn + b * HSTR + col) = pk;
            if (!last)
              __hip_atomic_store(xob + (b * 128 + wv * 8 + (l15 >> 1)), pk,
                                 __ATOMIC_RELAXED, __HIP_MEMORY_SCOPE_AGENT);
          }
        }
      }

      // stage x(t+1) before the end-of-step barrier
      if (l == NL - 1 && t < S_LEN - 1){
        float xv = xvalid ? x[xbase + (size_t)(t + 1) * IN_D] : 0.f;
        xpack[(t + 1) & 1][tid] = f2bf(xv);
      }

      if (!last){
        WAIT0;                                    // mailbox stores drained
        __syncthreads();
        if (tid == 0)
          __hip_atomic_store(&flags[bid], s + 1, __ATOMIC_RELAXED, __HIP_MEMORY_SCOPE_AGENT);
      }
      cur ^= 1;
    }
  }

#undef PREF
#undef WAIT3
#undef WAIT0
#undef CONSUME

  // epilogue: own 32r x 16c slice from registers
#pragma unroll
  for (int m = 0; m < 2; ++m)
#pragma unroll
    for (int q = 0; q < 4; ++q){
      int b = m * 16 + l4 * 4 + q;
      out[((size_t)(b0 + b)) * 512 + col] = hreg[m][q];
    }
}

extern "C" void kernel_launch(void* const* d_in, const int* in_sizes, int n_in,
                              void* d_out, int out_size, void* d_ws, size_t ws_size,
                              hipStream_t stream){
  const float* x   = (const float*)d_in[0];
  const float* Wih = (const float*)d_in[1];
  const float* Whh = (const float*)d_in[2];
  const float* bih = (const float*)d_in[3];
  const float* bhh = (const float*)d_in[4];

  unsigned char* ws = (unsigned char*)d_ws;
  unsigned short* Wp   = (unsigned short*)(ws + OFF_WHH);
  unsigned short* Wip  = (unsigned short*)(ws + OFF_WIH);
  int*            flg  = (int*)(ws + OFF_FLAG);
  unsigned int*   xchg = (unsigned int*)(ws + OFF_XCHG);

  hipMemsetAsync(flg, 0, 256 * sizeof(int), stream);   // generation flags start at 0 every call
  prep_whh <<<1152, 256, 0, stream>>>(Whh, Wp);
  prep_wih <<<  72, 256, 0, stream>>>(Wih, Wip);
  gru_main <<< 256, 1024, 0, stream>>>(x, Wp, Wip, bih, bhh, (float*)d_out, flg, xchg);
}